// Round 11
// baseline (355.441 us; speedup 1.0000x reference)
//
#include <hip/hip_runtime.h>
#include <hip/hip_bf16.h>
#include <math.h>

#define Bn   8
#define Ln   4096
#define DINn 128
#define Hn   256
#define N2n  8
#define NLn  4

typedef __attribute__((ext_vector_type(4))) float f32x4;
typedef __attribute__((ext_vector_type(8))) short bf16x8;

__device__ __forceinline__ float gelu_f(float x) {
    float x2 = x * x;
    float inner = 0.7978845608028654f * x * fmaf(0.044715f, x2, 1.0f);
    float e = __expf(2.0f * inner);
    float th = 1.0f - 2.0f / (e + 1.0f);
    return 0.5f * x * (1.0f + th);
}

__device__ __forceinline__ float sigmoid_f(float x) {
    return 1.0f / (1.0f + __expf(-x));
}

__device__ __forceinline__ unsigned short f2bf(float f) {
    union { __hip_bfloat16 b; unsigned short u; } cv;
    cv.b = __float2bfloat16(f);
    return cv.u;
}

__device__ __forceinline__ uint4 pack8(float4 a, float4 b) {
    uint4 v;
    v.x = (unsigned)f2bf(a.x) | ((unsigned)f2bf(a.y) << 16);
    v.y = (unsigned)f2bf(a.z) | ((unsigned)f2bf(a.w) << 16);
    v.z = (unsigned)f2bf(b.x) | ((unsigned)f2bf(b.y) << 16);
    v.w = (unsigned)f2bf(b.z) | ((unsigned)f2bf(b.w) << 16);
    return v;
}

// ---------------------------------------------------------------------------
// S4D scan (round-3 proven version, verbatim): y = gelu(conv(u,K) + D*u),
// one (b,h) row per WAVE via LDS-staged u, 64 elems/lane.
// grid (H/4, B), block 256 = 4 independent waves.
// ---------------------------------------------------------------------------
__global__ __launch_bounds__(256) void s4_scan_kernel(
    const float* __restrict__ hT,          // (B,H,L) f32
    unsigned short* __restrict__ yT,       // (B,H,L) bf16 out
    const float* __restrict__ log_dt,
    const float* __restrict__ log_A_real,
    const float* __restrict__ A_imag,
    const float* __restrict__ C_re,
    const float* __restrict__ C_im,
    const float* __restrict__ D_skip)
{
    __shared__ float u_lds[4][64][65];
    const int tid = threadIdx.x;
    const int v = tid >> 6;
    const int t = tid & 63;
    const int h = blockIdx.x * 4 + v;
    const int b = blockIdx.y;

    const size_t rowbase = (size_t)(b * Hn + h) * Ln + (size_t)t * 64;
    const float* src = hT + rowbase;
    float* uL = &u_lds[v][t][0];

    #pragma unroll
    for (int j4 = 0; j4 < 16; ++j4) {
        float4 g = *(const float4*)(src + j4 * 4);
        uL[j4 * 4 + 0] = g.x; uL[j4 * 4 + 1] = g.y;
        uL[j4 * 4 + 2] = g.z; uL[j4 * 4 + 3] = g.w;
    }

    float dt = expf(log_dt[h]);
    float wr[N2n], wi[N2n], cr[N2n], ci[N2n];
    #pragma unroll
    for (int n = 0; n < N2n; ++n) {
        float lar = log_A_real[h * N2n + n];
        float aim = A_imag[h * N2n + n];
        float are = -expf(lar);
        float dre = are * dt, dimv = aim * dt;
        float mag = expf(dre);
        float s_, c_;
        sincosf(dimv, &s_, &c_);
        float w_re = mag * c_, w_im = mag * s_;
        wr[n] = w_re; wi[n] = w_im;
        float nre = w_re - 1.0f, nim = w_im;
        float inv = 1.0f / (are * are + aim * aim);
        float tre = (nre * are + nim * aim) * inv;
        float tim = (nim * are - nre * aim) * inv;
        float Cr = C_re[h * N2n + n], Ci = C_im[h * N2n + n];
        cr[n] = Cr * tre - Ci * tim;
        ci[n] = Cr * tim + Ci * tre;
    }
    const float Dsk = D_skip[h];

    // ---- phase 1: local scan (zero init); y_loc + D*u overwrites u in LDS ----
    float sr[N2n], si[N2n];
    #pragma unroll
    for (int n = 0; n < N2n; ++n) { sr[n] = 0.0f; si[n] = 0.0f; }
    #pragma unroll 4
    for (int j = 0; j < 64; ++j) {
        float u = uL[j];
        float acc = 0.0f;
        #pragma unroll
        for (int n = 0; n < N2n; ++n) {
            float nr = fmaf(wr[n], sr[n], fmaf(-wi[n], si[n], u));
            float ni = fmaf(wi[n], sr[n], wr[n] * si[n]);
            sr[n] = nr; si[n] = ni;
            acc = fmaf(cr[n], nr, fmaf(-ci[n], ni, acc));
        }
        uL[j] = fmaf(2.0f, acc, Dsk * u);
    }

    // ---- phase 2: inclusive wave scan of end-states, multiplier w^64 ----
    float mr[N2n], mi[N2n];
    #pragma unroll
    for (int n = 0; n < N2n; ++n) {
        float ar = wr[n], ai = wi[n];
        #pragma unroll
        for (int q = 0; q < 6; ++q) { float nr2 = ar * ar - ai * ai; ai = 2.0f * ar * ai; ar = nr2; }
        mr[n] = ar; mi[n] = ai;   // w^64
    }
    for (int dlt = 1; dlt < 64; dlt <<= 1) {
        #pragma unroll
        for (int n = 0; n < N2n; ++n) {
            float tr = __shfl_up(sr[n], (unsigned)dlt, 64);
            float ti = __shfl_up(si[n], (unsigned)dlt, 64);
            float trz = (t >= dlt) ? tr : 0.0f;
            float tiz = (t >= dlt) ? ti : 0.0f;
            sr[n] = fmaf(mr[n], trz, fmaf(-mi[n], tiz, sr[n]));
            si[n] = fmaf(mr[n], tiz, fmaf(mi[n], trz, si[n]));
        }
        #pragma unroll
        for (int n = 0; n < N2n; ++n) {
            float nr2 = mr[n] * mr[n] - mi[n] * mi[n];
            mi[n] = 2.0f * mr[n] * mi[n];
            mr[n] = nr2;
        }
    }
    float pr[N2n], pim[N2n];
    #pragma unroll
    for (int n = 0; n < N2n; ++n) {
        float er = __shfl_up(sr[n], 1u, 64);
        float ei = __shfl_up(si[n], 1u, 64);
        pr[n]  = (t >= 1) ? er : 0.0f;
        pim[n] = (t >= 1) ? ei : 0.0f;
    }

    // ---- phase 3: add correction 2*Re(Ck * w^(j+1) * p), gelu, store bf16 ----
    float dr2[N2n], di2[N2n];
    #pragma unroll
    for (int n = 0; n < N2n; ++n) { dr2[n] = cr[n]; di2[n] = ci[n]; }
    unsigned short* dst = yT + rowbase;
    for (int j8 = 0; j8 < 8; ++j8) {
        unsigned short rs[8];
        #pragma unroll
        for (int c = 0; c < 8; ++c) {
            float corr = 0.0f;
            #pragma unroll
            for (int n = 0; n < N2n; ++n) {
                float nr2 = dr2[n] * wr[n] - di2[n] * wi[n];
                float ni2 = dr2[n] * wi[n] + di2[n] * wr[n];
                dr2[n] = nr2; di2[n] = ni2;
                corr = fmaf(nr2, pr[n], fmaf(-ni2, pim[n], corr));
            }
            float yv = fmaf(2.0f, corr, uL[j8 * 8 + c]);
            rs[c] = f2bf(gelu_f(yv));
        }
        uint4 o;
        o.x = (unsigned)rs[0] | ((unsigned)rs[1] << 16);
        o.y = (unsigned)rs[2] | ((unsigned)rs[3] << 16);
        o.z = (unsigned)rs[4] | ((unsigned)rs[5] << 16);
        o.w = (unsigned)rs[6] | ((unsigned)rs[7] << 16);
        *(uint4*)(dst + j8 * 8) = o;
    }
}

// ---------------------------------------------------------------------------
// t16: yT (b, 256, 4096) bf16 -> yN (b, 4096, 256) bf16.  64x64 LDS tile.
// ---------------------------------------------------------------------------
__global__ __launch_bounds__(256) void t16_kernel(
    const unsigned short* __restrict__ src, unsigned short* __restrict__ dst)
{
    __shared__ unsigned short tl[64 * 66];
    const int tid = threadIdx.x;
    const int l0 = blockIdx.x * 64, h0 = blockIdx.y * 64, b = blockIdx.z;
    #pragma unroll
    for (int it = 0; it < 2; ++it) {
        int idx = it * 256 + tid; int r = idx >> 3, c8 = idx & 7;
        uint4 g = *(const uint4*)(src + ((size_t)(b * Hn + h0 + r)) * Ln + l0 + c8 * 8);
        unsigned short* p = &tl[r * 66 + c8 * 8];
        p[0] = g.x & 0xffff; p[1] = g.x >> 16;
        p[2] = g.y & 0xffff; p[3] = g.y >> 16;
        p[4] = g.z & 0xffff; p[5] = g.z >> 16;
        p[6] = g.w & 0xffff; p[7] = g.w >> 16;
    }
    __syncthreads();
    #pragma unroll
    for (int it = 0; it < 2; ++it) {
        int idx = it * 256 + tid; int hc = idx & 7, lr = idx >> 3;
        unsigned short e[8];
        #pragma unroll
        for (int j = 0; j < 8; ++j) e[j] = tl[(hc * 8 + j) * 66 + lr];
        uint4 o;
        o.x = (unsigned)e[0] | ((unsigned)e[1] << 16);
        o.y = (unsigned)e[2] | ((unsigned)e[3] << 16);
        o.z = (unsigned)e[4] | ((unsigned)e[5] << 16);
        o.w = (unsigned)e[6] | ((unsigned)e[7] << 16);
        *(uint4*)(dst + ((size_t)(b * Ln + l0 + lr)) * Hn + h0 + hc * 8) = o;
    }
}

// ---------------------------------------------------------------------------
// MFMA GEMM: C(M,256) = A(M,KDIM) @ W^T (+bias,+GLU,+resid).
// 128x128 tile, BK=64, 4 waves (2x2, each 64x64), mfma_f32_16x16x32_bf16.
// Grid (M/128, 256/128) = (256, 2) -> exactly 2 blocks/CU.
// WRT: also writes transposed HTout (B,256,L) f32 via reused LDS tile
// (pitch 132 f32 -> no 16-way bank conflict on the transposed write).
// ---------------------------------------------------------------------------
template<int KDIM, bool GLU, bool ACVT, bool WRT>
__global__ __launch_bounds__(256, 2) void mfma_gemm(
    const unsigned short* __restrict__ Abf,
    const float* __restrict__ Af,
    const float* __restrict__ W,
    const float* __restrict__ ba,
    const float* __restrict__ bg,
    const float* resid,              // aliases Hout (read-before-write, block-owned)
    float* Hout,                     // (M,256)
    float* HTout)                    // (B,256,L) f32
{
    constexpr int SM_MAIN = (GLU ? 3 : 2) * 128 * 72 * 2;
    constexpr int SM_TS = WRT ? (128 * 132 * 4) : 0;
    constexpr int SM = SM_MAIN > SM_TS ? SM_MAIN : SM_TS;
    __shared__ __align__(16) char smem[SM];
    unsigned short* As  = (unsigned short*)smem;
    unsigned short* Bs0 = As + 128 * 72;
    unsigned short* Bs1 = Bs0 + 128 * 72;  // GLU only
    float* ts = (float*)smem;              // reused after k-loop (WRT)

    const int tid = threadIdx.x;
    const int lane = tid & 63, w = tid >> 6;
    const int wm = w >> 1, wn = w & 1;
    const int lr = lane & 15, lq = lane >> 4;
    const int row0 = blockIdx.x * 128;
    const int n0 = blockIdx.y * 128;
    const int bb = row0 >> 12;
    const int l0 = row0 & (Ln - 1);

    f32x4 accA[4][4], accG[4][4];
    #pragma unroll
    for (int i = 0; i < 4; ++i)
        #pragma unroll
        for (int j = 0; j < 4; ++j) {
            accA[i][j] = (f32x4)0.0f;
            if constexpr (GLU) accG[i][j] = (f32x4)0.0f;
        }

    for (int kt = 0; kt < KDIM / 64; ++kt) {
        const int k0 = kt * 64;
        // ---- stage A (128 rows x 64 k) ----
        #pragma unroll
        for (int it = 0; it < 4; ++it) {
            int idx = it * 256 + tid; int m = idx >> 3, q = idx & 7;
            uint4 vv;
            if constexpr (ACVT) {
                const float* s = Af + (size_t)(row0 + m) * KDIM + k0 + q * 8;
                float4 g1 = *(const float4*)s;
                float4 g2 = *(const float4*)(s + 4);
                vv = pack8(g1, g2);
            } else {
                vv = *(const uint4*)(Abf + (size_t)(row0 + m) * KDIM + k0 + q * 8);
            }
            *(uint4*)(&As[m * 72 + q * 8]) = vv;
        }
        // ---- stage B (128 rows x 64 k, f32 -> bf16), x2 for GLU ----
        #pragma unroll
        for (int it = 0; it < 4; ++it) {
            int idx = it * 256 + tid; int p = idx >> 3, q = idx & 7;
            {
                const float* s = W + (size_t)(n0 + p) * KDIM + k0 + q * 8;
                float4 g1 = *(const float4*)s;
                float4 g2 = *(const float4*)(s + 4);
                *(uint4*)(&Bs0[p * 72 + q * 8]) = pack8(g1, g2);
            }
            if constexpr (GLU) {
                const float* s = W + (size_t)(256 + n0 + p) * KDIM + k0 + q * 8;
                float4 g1 = *(const float4*)s;
                float4 g2 = *(const float4*)(s + 4);
                *(uint4*)(&Bs1[p * 72 + q * 8]) = pack8(g1, g2);
            }
        }
        __syncthreads();
        // ---- MFMA: wave tile 64x64 ----
        #pragma unroll
        for (int kf = 0; kf < 2; ++kf) {
            bf16x8 av[4], bv[4], gv[4];
            #pragma unroll
            for (int mf = 0; mf < 4; ++mf)
                av[mf] = *(const bf16x8*)(&As[(wm * 64 + mf * 16 + lr) * 72 + (kf * 4 + lq) * 8]);
            #pragma unroll
            for (int nf = 0; nf < 4; ++nf) {
                bv[nf] = *(const bf16x8*)(&Bs0[(wn * 64 + nf * 16 + lr) * 72 + (kf * 4 + lq) * 8]);
                if constexpr (GLU)
                    gv[nf] = *(const bf16x8*)(&Bs1[(wn * 64 + nf * 16 + lr) * 72 + (kf * 4 + lq) * 8]);
            }
            #pragma unroll
            for (int mf = 0; mf < 4; ++mf)
                #pragma unroll
                for (int nf = 0; nf < 4; ++nf) {
                    accA[mf][nf] = __builtin_amdgcn_mfma_f32_16x16x32_bf16(av[mf], bv[nf], accA[mf][nf], 0, 0, 0);
                    if constexpr (GLU)
                        accG[mf][nf] = __builtin_amdgcn_mfma_f32_16x16x32_bf16(av[mf], gv[nf], accG[mf][nf], 0, 0, 0);
                }
        }
        __syncthreads();
    }

    // ---- epilogue ----
    int pc[4]; float bA[4], bG[4];
    #pragma unroll
    for (int nf = 0; nf < 4; ++nf) {
        pc[nf] = n0 + wn * 64 + nf * 16 + lr;
        bA[nf] = ba[pc[nf]];
        if constexpr (GLU) bG[nf] = bg[pc[nf]];
    }
    #pragma unroll
    for (int mf = 0; mf < 4; ++mf) {
        #pragma unroll
        for (int r = 0; r < 4; ++r) {
            int m_loc = wm * 64 + mf * 16 + lq * 4 + r;
            size_t rbase = (size_t)(row0 + m_loc) * Hn;
            #pragma unroll
            for (int nf = 0; nf < 4; ++nf) {
                float o;
                if constexpr (GLU) {
                    float aval = accA[mf][nf][r] + bA[nf];
                    float gval = accG[mf][nf][r] + bG[nf];
                    o = aval * sigmoid_f(gval) + resid[rbase + pc[nf]];
                } else {
                    o = accA[mf][nf][r] + bA[nf];
                }
                Hout[rbase + pc[nf]] = o;
                if constexpr (WRT)
                    ts[(wn * 64 + nf * 16 + lr) * 132 + m_loc] = o;
            }
        }
    }
    if constexpr (WRT) {
        __syncthreads();
        #pragma unroll
        for (int it = 0; it < 16; ++it) {
            int idx = it * 256 + tid;
            int nn = idx >> 5, m4 = (idx & 31) * 4;
            float4 o = *(const float4*)(&ts[nn * 132 + m4]);
            *(float4*)(HTout + (size_t)(bb * Hn + n0 + nn) * Ln + l0 + m4) = o;
        }
    }
}

extern "C" void kernel_launch(void* const* d_in, const int* in_sizes, int n_in,
                              void* d_out, int out_size, void* d_ws, size_t ws_size,
                              hipStream_t stream) {
    (void)in_sizes; (void)n_in; (void)out_size; (void)ws_size;
    const float* x          = (const float*)d_in[0];
    const float* enc_w      = (const float*)d_in[1];
    const float* enc_b      = (const float*)d_in[2];
    const float* log_dt     = (const float*)d_in[3];
    const float* log_A_real = (const float*)d_in[4];
    const float* A_imag     = (const float*)d_in[5];
    const float* C_re       = (const float*)d_in[6];
    const float* C_im       = (const float*)d_in[7];
    const float* D_skip     = (const float*)d_in[8];
    const float* out_w      = (const float*)d_in[9];
    const float* out_b      = (const float*)d_in[10];

    const size_t NE = (size_t)Bn * Hn * Ln;
    float* h  = (float*)d_out;                        // (B,L,H) residual stream
    float* hT = (float*)d_ws;                         // (B,H,L) f32
    unsigned short* yT = (unsigned short*)(hT + NE);  // (B,H,L) bf16
    unsigned short* yN = yT + NE;                     // (B,L,H) bf16

    const dim3 gb(256);

    // encoder: h,hT = x @ enc_w^T + enc_b
    mfma_gemm<DINn, false, true, true><<<dim3(256, 2), gb, 0, stream>>>(
        nullptr, x, enc_w, enc_b, nullptr, nullptr, h, hT);

    for (int i = 0; i < NLn; ++i) {
        s4_scan_kernel<<<dim3(Hn / 4, Bn), gb, 0, stream>>>(
            hT, yT,
            log_dt + (size_t)i * Hn,
            log_A_real + (size_t)i * Hn * N2n,
            A_imag + (size_t)i * Hn * N2n,
            C_re + (size_t)i * Hn * N2n,
            C_im + (size_t)i * Hn * N2n,
            D_skip + (size_t)i * Hn);
        t16_kernel<<<dim3(64, 4, 8), gb, 0, stream>>>(yT, yN);
        const float* wlay = out_w + (size_t)i * 2 * Hn * Hn;
        const float* bl = out_b + (size_t)i * 2 * Hn;
        if (i == NLn - 1) {
            mfma_gemm<Hn, true, false, false><<<dim3(256, 2), gb, 0, stream>>>(
                yN, nullptr, wlay, bl, bl + Hn, h, h, nullptr);
        } else {
            mfma_gemm<Hn, true, false, true><<<dim3(256, 2), gb, 0, stream>>>(
                yN, nullptr, wlay, bl, bl + Hn, h, h, hT);
        }
    }
}

// Round 12
// 340.885 us; speedup vs baseline: 1.0427x; 1.0427x over previous
//
#include <hip/hip_runtime.h>
#include <hip/hip_bf16.h>
#include <math.h>

#define Bn   8
#define Ln   4096
#define DINn 128
#define Hn   256
#define N2n  8
#define NLn  4

typedef __attribute__((ext_vector_type(4))) float f32x4;
typedef __attribute__((ext_vector_type(8))) short bf16x8;

__device__ __forceinline__ float gelu_f(float x) {
    float x2 = x * x;
    float inner = 0.7978845608028654f * x * fmaf(0.044715f, x2, 1.0f);
    float e = __expf(2.0f * inner);
    float th = 1.0f - 2.0f / (e + 1.0f);
    return 0.5f * x * (1.0f + th);
}

__device__ __forceinline__ float sigmoid_f(float x) {
    return 1.0f / (1.0f + __expf(-x));
}

__device__ __forceinline__ unsigned short f2bf(float f) {
    union { __hip_bfloat16 b; unsigned short u; } cv;
    cv.b = __float2bfloat16(f);
    return cv.u;
}

__device__ __forceinline__ uint4 pack8(float4 a, float4 b) {
    uint4 v;
    v.x = (unsigned)f2bf(a.x) | ((unsigned)f2bf(a.y) << 16);
    v.y = (unsigned)f2bf(a.z) | ((unsigned)f2bf(a.w) << 16);
    v.z = (unsigned)f2bf(b.x) | ((unsigned)f2bf(b.y) << 16);
    v.w = (unsigned)f2bf(b.z) | ((unsigned)f2bf(b.w) << 16);
    return v;
}

// ---------------------------------------------------------------------------
// S4D scan (round-3 proven version, verbatim): y = gelu(conv(u,K) + D*u),
// one (b,h) row per WAVE via LDS-staged u, 64 elems/lane.
// grid (H/4, B), block 256 = 4 independent waves.
// ---------------------------------------------------------------------------
__global__ __launch_bounds__(256) void s4_scan_kernel(
    const float* __restrict__ hT,          // (B,H,L) f32
    unsigned short* __restrict__ yT,       // (B,H,L) bf16 out
    const float* __restrict__ log_dt,
    const float* __restrict__ log_A_real,
    const float* __restrict__ A_imag,
    const float* __restrict__ C_re,
    const float* __restrict__ C_im,
    const float* __restrict__ D_skip)
{
    __shared__ float u_lds[4][64][65];
    const int tid = threadIdx.x;
    const int v = tid >> 6;
    const int t = tid & 63;
    const int h = blockIdx.x * 4 + v;
    const int b = blockIdx.y;

    const size_t rowbase = (size_t)(b * Hn + h) * Ln + (size_t)t * 64;
    const float* src = hT + rowbase;
    float* uL = &u_lds[v][t][0];

    #pragma unroll
    for (int j4 = 0; j4 < 16; ++j4) {
        float4 g = *(const float4*)(src + j4 * 4);
        uL[j4 * 4 + 0] = g.x; uL[j4 * 4 + 1] = g.y;
        uL[j4 * 4 + 2] = g.z; uL[j4 * 4 + 3] = g.w;
    }

    float dt = expf(log_dt[h]);
    float wr[N2n], wi[N2n], cr[N2n], ci[N2n];
    #pragma unroll
    for (int n = 0; n < N2n; ++n) {
        float lar = log_A_real[h * N2n + n];
        float aim = A_imag[h * N2n + n];
        float are = -expf(lar);
        float dre = are * dt, dimv = aim * dt;
        float mag = expf(dre);
        float s_, c_;
        sincosf(dimv, &s_, &c_);
        float w_re = mag * c_, w_im = mag * s_;
        wr[n] = w_re; wi[n] = w_im;
        float nre = w_re - 1.0f, nim = w_im;
        float inv = 1.0f / (are * are + aim * aim);
        float tre = (nre * are + nim * aim) * inv;
        float tim = (nim * are - nre * aim) * inv;
        float Cr = C_re[h * N2n + n], Ci = C_im[h * N2n + n];
        cr[n] = Cr * tre - Ci * tim;
        ci[n] = Cr * tim + Ci * tre;
    }
    const float Dsk = D_skip[h];

    // ---- phase 1: local scan (zero init); y_loc + D*u overwrites u in LDS ----
    float sr[N2n], si[N2n];
    #pragma unroll
    for (int n = 0; n < N2n; ++n) { sr[n] = 0.0f; si[n] = 0.0f; }
    #pragma unroll 4
    for (int j = 0; j < 64; ++j) {
        float u = uL[j];
        float acc = 0.0f;
        #pragma unroll
        for (int n = 0; n < N2n; ++n) {
            float nr = fmaf(wr[n], sr[n], fmaf(-wi[n], si[n], u));
            float ni = fmaf(wi[n], sr[n], wr[n] * si[n]);
            sr[n] = nr; si[n] = ni;
            acc = fmaf(cr[n], nr, fmaf(-ci[n], ni, acc));
        }
        uL[j] = fmaf(2.0f, acc, Dsk * u);
    }

    // ---- phase 2: inclusive wave scan of end-states, multiplier w^64 ----
    float mr[N2n], mi[N2n];
    #pragma unroll
    for (int n = 0; n < N2n; ++n) {
        float ar = wr[n], ai = wi[n];
        #pragma unroll
        for (int q = 0; q < 6; ++q) { float nr2 = ar * ar - ai * ai; ai = 2.0f * ar * ai; ar = nr2; }
        mr[n] = ar; mi[n] = ai;   // w^64
    }
    for (int dlt = 1; dlt < 64; dlt <<= 1) {
        #pragma unroll
        for (int n = 0; n < N2n; ++n) {
            float tr = __shfl_up(sr[n], (unsigned)dlt, 64);
            float ti = __shfl_up(si[n], (unsigned)dlt, 64);
            float trz = (t >= dlt) ? tr : 0.0f;
            float tiz = (t >= dlt) ? ti : 0.0f;
            sr[n] = fmaf(mr[n], trz, fmaf(-mi[n], tiz, sr[n]));
            si[n] = fmaf(mr[n], tiz, fmaf(mi[n], trz, si[n]));
        }
        #pragma unroll
        for (int n = 0; n < N2n; ++n) {
            float nr2 = mr[n] * mr[n] - mi[n] * mi[n];
            mi[n] = 2.0f * mr[n] * mi[n];
            mr[n] = nr2;
        }
    }
    float pr[N2n], pim[N2n];
    #pragma unroll
    for (int n = 0; n < N2n; ++n) {
        float er = __shfl_up(sr[n], 1u, 64);
        float ei = __shfl_up(si[n], 1u, 64);
        pr[n]  = (t >= 1) ? er : 0.0f;
        pim[n] = (t >= 1) ? ei : 0.0f;
    }

    // ---- phase 3: add correction 2*Re(Ck * w^(j+1) * p), gelu, store bf16 ----
    float dr2[N2n], di2[N2n];
    #pragma unroll
    for (int n = 0; n < N2n; ++n) { dr2[n] = cr[n]; di2[n] = ci[n]; }
    unsigned short* dst = yT + rowbase;
    for (int j8 = 0; j8 < 8; ++j8) {
        unsigned short rs[8];
        #pragma unroll
        for (int c = 0; c < 8; ++c) {
            float corr = 0.0f;
            #pragma unroll
            for (int n = 0; n < N2n; ++n) {
                float nr2 = dr2[n] * wr[n] - di2[n] * wi[n];
                float ni2 = dr2[n] * wi[n] + di2[n] * wr[n];
                dr2[n] = nr2; di2[n] = ni2;
                corr = fmaf(nr2, pr[n], fmaf(-ni2, pim[n], corr));
            }
            float yv = fmaf(2.0f, corr, uL[j8 * 8 + c]);
            rs[c] = f2bf(gelu_f(yv));
        }
        uint4 o;
        o.x = (unsigned)rs[0] | ((unsigned)rs[1] << 16);
        o.y = (unsigned)rs[2] | ((unsigned)rs[3] << 16);
        o.z = (unsigned)rs[4] | ((unsigned)rs[5] << 16);
        o.w = (unsigned)rs[6] | ((unsigned)rs[7] << 16);
        *(uint4*)(dst + j8 * 8) = o;
    }
}

// ---------------------------------------------------------------------------
// t16: yT (b, 256, 4096) bf16 -> yN (b, 4096, 256) bf16.  64x64 LDS tile.
// ---------------------------------------------------------------------------
__global__ __launch_bounds__(256) void t16_kernel(
    const unsigned short* __restrict__ src, unsigned short* __restrict__ dst)
{
    __shared__ unsigned short tl[64 * 66];
    const int tid = threadIdx.x;
    const int l0 = blockIdx.x * 64, h0 = blockIdx.y * 64, b = blockIdx.z;
    #pragma unroll
    for (int it = 0; it < 2; ++it) {
        int idx = it * 256 + tid; int r = idx >> 3, c8 = idx & 7;
        uint4 g = *(const uint4*)(src + ((size_t)(b * Hn + h0 + r)) * Ln + l0 + c8 * 8);
        unsigned short* p = &tl[r * 66 + c8 * 8];
        p[0] = g.x & 0xffff; p[1] = g.x >> 16;
        p[2] = g.y & 0xffff; p[3] = g.y >> 16;
        p[4] = g.z & 0xffff; p[5] = g.z >> 16;
        p[6] = g.w & 0xffff; p[7] = g.w >> 16;
    }
    __syncthreads();
    #pragma unroll
    for (int it = 0; it < 2; ++it) {
        int idx = it * 256 + tid; int hc = idx & 7, lr = idx >> 3;
        unsigned short e[8];
        #pragma unroll
        for (int j = 0; j < 8; ++j) e[j] = tl[(hc * 8 + j) * 66 + lr];
        uint4 o;
        o.x = (unsigned)e[0] | ((unsigned)e[1] << 16);
        o.y = (unsigned)e[2] | ((unsigned)e[3] << 16);
        o.z = (unsigned)e[4] | ((unsigned)e[5] << 16);
        o.w = (unsigned)e[6] | ((unsigned)e[7] << 16);
        *(uint4*)(dst + ((size_t)(b * Ln + l0 + lr)) * Hn + h0 + hc * 8) = o;
    }
}

// ---------------------------------------------------------------------------
// MFMA GEMM: C(M,256) = A(M,KDIM) @ W^T (+bias,+GLU,+resid).
// 128x64 tile, BK=64, 4 waves (2x2), mfma_f32_16x16x32_bf16.
// A-tile (bf16 path): staged via global_load_lds width=16 into LINEAR LDS
// [128][64] (async DMA; HBM latency overlaps B reg-staging).
// ACVT (encoder): A reg-staged with f32->bf16 into the same linear layout.
// B-tiles (f32 weights, L2-resident): reg-staged into pitch-72 LDS.
// WRT: also writes transposed HTout (B,256,L) via reused pitch-132 LDS tile.
// Grid (M/128, 256/64) = (256, 4) -> 4 blocks/CU (LDS 34KB).
// ---------------------------------------------------------------------------
template<int KDIM, bool GLU, bool ACVT, bool WRT>
__global__ __launch_bounds__(256) void mfma_gemm(
    const unsigned short* __restrict__ Abf,
    const float* __restrict__ Af,
    const float* __restrict__ W,
    const float* __restrict__ ba,
    const float* __restrict__ bg,
    const float* resid,              // aliases Hout (read-before-write, block-owned)
    float* Hout,                     // (M,256)
    float* HTout)                    // (B,256,L) f32
{
    constexpr int SM_MAIN = 128 * 64 * 2 + (GLU ? 2 : 1) * 64 * 72 * 2;
    constexpr int SM_TS = WRT ? (64 * 132 * 4) : 0;
    constexpr int SM = SM_MAIN > SM_TS ? SM_MAIN : SM_TS;
    __shared__ __align__(16) char smem[SM];
    unsigned short* As  = (unsigned short*)smem;   // [128][64] LINEAR (gload dest)
    unsigned short* Bs0 = As + 128 * 64;           // [64][72]
    unsigned short* Bs1 = Bs0 + 64 * 72;           // GLU only
    float* ts = (float*)smem;                      // reused after k-loop (WRT)

    const int tid = threadIdx.x;
    const int lane = tid & 63, w = tid >> 6;
    const int wm = w >> 1, wn = w & 1;
    const int lr = lane & 15, lq = lane >> 4;
    const int row0 = blockIdx.x * 128;
    const int n0 = blockIdx.y * 64;
    const int bb = row0 >> 12;
    const int l0 = row0 & (Ln - 1);

    f32x4 accA[4][2], accG[4][2];
    #pragma unroll
    for (int i = 0; i < 4; ++i)
        #pragma unroll
        for (int j = 0; j < 2; ++j) {
            accA[i][j] = (f32x4)0.0f;
            if constexpr (GLU) accG[i][j] = (f32x4)0.0f;
        }

    for (int kt = 0; kt < KDIM / 64; ++kt) {
        const int k0 = kt * 64;
        // ---- stage A first (async when bf16): HBM latency overlaps B staging ----
        if constexpr (ACVT) {
            #pragma unroll
            for (int it = 0; it < 4; ++it) {
                int idx = it * 256 + tid; int m = idx >> 3, q = idx & 7;
                const float* s = Af + (size_t)(row0 + m) * KDIM + k0 + q * 8;
                float4 g1 = *(const float4*)s;
                float4 g2 = *(const float4*)(s + 4);
                *(uint4*)(&As[m * 64 + q * 8]) = pack8(g1, g2);
            }
        } else {
            // wave w covers rows [w*32, w*32+32): 4 DMA insts x 8 rows each.
            // dest = uniform base + lane*16B: lane = r*8+q -> row +r, bytes q*16.
            #pragma unroll
            for (int i = 0; i < 4; ++i) {
                int rowloc = w * 32 + i * 8 + (lane >> 3);
                const unsigned short* g =
                    Abf + (size_t)(row0 + rowloc) * KDIM + k0 + (lane & 7) * 8;
                unsigned short* l = As + (w * 32 + i * 8) * 64;
                __builtin_amdgcn_global_load_lds(
                    (const __attribute__((address_space(1))) void*)g,
                    (__attribute__((address_space(3))) void*)l, 16, 0, 0);
            }
        }
        // ---- stage B (64 rows x 64 k, f32 -> bf16, L2-resident weights) ----
        #pragma unroll
        for (int it = 0; it < 2; ++it) {
            int idx = it * 256 + tid; int p = idx >> 3, q = idx & 7;
            {
                const float* s = W + (size_t)(n0 + p) * KDIM + k0 + q * 8;
                float4 g1 = *(const float4*)s;
                float4 g2 = *(const float4*)(s + 4);
                *(uint4*)(&Bs0[p * 72 + q * 8]) = pack8(g1, g2);
            }
            if constexpr (GLU) {
                const float* s = W + (size_t)(256 + n0 + p) * KDIM + k0 + q * 8;
                float4 g1 = *(const float4*)s;
                float4 g2 = *(const float4*)(s + 4);
                *(uint4*)(&Bs1[p * 72 + q * 8]) = pack8(g1, g2);
            }
        }
        __syncthreads();   // drains vmcnt (incl. global_load_lds) + lgkmcnt
        // ---- MFMA: wave tile 64x32 ----
        #pragma unroll
        for (int kf = 0; kf < 2; ++kf) {
            bf16x8 av[4], bv[2], gv[2];
            #pragma unroll
            for (int mf = 0; mf < 4; ++mf)
                av[mf] = *(const bf16x8*)(&As[(wm * 64 + mf * 16 + lr) * 64 + (kf * 4 + lq) * 8]);
            #pragma unroll
            for (int nf = 0; nf < 2; ++nf) {
                bv[nf] = *(const bf16x8*)(&Bs0[(wn * 32 + nf * 16 + lr) * 72 + (kf * 4 + lq) * 8]);
                if constexpr (GLU)
                    gv[nf] = *(const bf16x8*)(&Bs1[(wn * 32 + nf * 16 + lr) * 72 + (kf * 4 + lq) * 8]);
            }
            #pragma unroll
            for (int mf = 0; mf < 4; ++mf)
                #pragma unroll
                for (int nf = 0; nf < 2; ++nf) {
                    accA[mf][nf] = __builtin_amdgcn_mfma_f32_16x16x32_bf16(av[mf], bv[nf], accA[mf][nf], 0, 0, 0);
                    if constexpr (GLU)
                        accG[mf][nf] = __builtin_amdgcn_mfma_f32_16x16x32_bf16(av[mf], gv[nf], accG[mf][nf], 0, 0, 0);
                }
        }
        __syncthreads();
    }

    // ---- epilogue ----
    int pc[2]; float bA[2], bG[2];
    #pragma unroll
    for (int nf = 0; nf < 2; ++nf) {
        pc[nf] = n0 + wn * 32 + nf * 16 + lr;
        bA[nf] = ba[pc[nf]];
        if constexpr (GLU) bG[nf] = bg[pc[nf]];
    }
    #pragma unroll
    for (int mf = 0; mf < 4; ++mf) {
        #pragma unroll
        for (int r = 0; r < 4; ++r) {
            int m_loc = wm * 64 + mf * 16 + lq * 4 + r;
            size_t rbase = (size_t)(row0 + m_loc) * Hn;
            #pragma unroll
            for (int nf = 0; nf < 2; ++nf) {
                float o;
                if constexpr (GLU) {
                    float aval = accA[mf][nf][r] + bA[nf];
                    float gval = accG[mf][nf][r] + bG[nf];
                    o = aval * sigmoid_f(gval) + resid[rbase + pc[nf]];
                } else {
                    o = accA[mf][nf][r] + bA[nf];
                }
                Hout[rbase + pc[nf]] = o;
                if constexpr (WRT)
                    ts[(wn * 32 + nf * 16 + lr) * 132 + m_loc] = o;
            }
        }
    }
    if constexpr (WRT) {
        __syncthreads();
        #pragma unroll
        for (int it = 0; it < 8; ++it) {
            int idx = it * 256 + tid;
            int nn = idx >> 5, m4 = (idx & 31) * 4;
            float4 o = *(const float4*)(&ts[nn * 132 + m4]);
            *(float4*)(HTout + (size_t)(bb * Hn + n0 + nn) * Ln + l0 + m4) = o;
        }
    }
}

extern "C" void kernel_launch(void* const* d_in, const int* in_sizes, int n_in,
                              void* d_out, int out_size, void* d_ws, size_t ws_size,
                              hipStream_t stream) {
    (void)in_sizes; (void)n_in; (void)out_size; (void)ws_size;
    const float* x          = (const float*)d_in[0];
    const float* enc_w      = (const float*)d_in[1];
    const float* enc_b      = (const float*)d_in[2];
    const float* log_dt     = (const float*)d_in[3];
    const float* log_A_real = (const float*)d_in[4];
    const float* A_imag     = (const float*)d_in[5];
    const float* C_re       = (const float*)d_in[6];
    const float* C_im       = (const float*)d_in[7];
    const float* D_skip     = (const float*)d_in[8];
    const float* out_w      = (const float*)d_in[9];
    const float* out_b      = (const float*)d_in[10];

    const size_t NE = (size_t)Bn * Hn * Ln;
    float* h  = (float*)d_out;                        // (B,L,H) residual stream
    float* hT = (float*)d_ws;                         // (B,H,L) f32
    unsigned short* yT = (unsigned short*)(hT + NE);  // (B,H,L) bf16
    unsigned short* yN = yT + NE;                     // (B,L,H) bf16

    const dim3 gb(256);

    // encoder: h,hT = x @ enc_w^T + enc_b
    mfma_gemm<DINn, false, true, true><<<dim3(256, 4), gb, 0, stream>>>(
        nullptr, x, enc_w, enc_b, nullptr, nullptr, h, hT);

    for (int i = 0; i < NLn; ++i) {
        s4_scan_kernel<<<dim3(Hn / 4, Bn), gb, 0, stream>>>(
            hT, yT,
            log_dt + (size_t)i * Hn,
            log_A_real + (size_t)i * Hn * N2n,
            A_imag + (size_t)i * Hn * N2n,
            C_re + (size_t)i * Hn * N2n,
            C_im + (size_t)i * Hn * N2n,
            D_skip + (size_t)i * Hn);
        t16_kernel<<<dim3(64, 4, 8), gb, 0, stream>>>(yT, yN);
        const float* wlay = out_w + (size_t)i * 2 * Hn * Hn;
        const float* bl = out_b + (size_t)i * 2 * Hn;
        if (i == NLn - 1) {
            mfma_gemm<Hn, true, false, false><<<dim3(256, 4), gb, 0, stream>>>(
                yN, nullptr, wlay, bl, bl + Hn, h, h, nullptr);
        } else {
            mfma_gemm<Hn, true, false, true><<<dim3(256, 4), gb, 0, stream>>>(
                yN, nullptr, wlay, bl, bl + Hn, h, h, hT);
        }
    }
}

// Round 13
// 286.790 us; speedup vs baseline: 1.2394x; 1.1886x over previous
//
#include <hip/hip_runtime.h>
#include <hip/hip_bf16.h>
#include <math.h>

#define Bn   8
#define Ln   4096
#define DINn 128
#define Hn   256
#define N2n  8
#define NLn  4

typedef __attribute__((ext_vector_type(4))) float f32x4;
typedef __attribute__((ext_vector_type(8))) short bf16x8;

__device__ __forceinline__ float gelu_f(float x) {
    float x2 = x * x;
    float inner = 0.7978845608028654f * x * fmaf(0.044715f, x2, 1.0f);
    float e = __expf(2.0f * inner);
    float th = 1.0f - 2.0f / (e + 1.0f);
    return 0.5f * x * (1.0f + th);
}

__device__ __forceinline__ float sigmoid_f(float x) {
    return 1.0f / (1.0f + __expf(-x));
}

__device__ __forceinline__ unsigned short f2bf(float f) {
    union { __hip_bfloat16 b; unsigned short u; } cv;
    cv.b = __float2bfloat16(f);
    return cv.u;
}

__device__ __forceinline__ uint4 pack8(float4 a, float4 b) {
    uint4 v;
    v.x = (unsigned)f2bf(a.x) | ((unsigned)f2bf(a.y) << 16);
    v.y = (unsigned)f2bf(a.z) | ((unsigned)f2bf(a.w) << 16);
    v.z = (unsigned)f2bf(b.x) | ((unsigned)f2bf(b.y) << 16);
    v.w = (unsigned)f2bf(b.z) | ((unsigned)f2bf(b.w) << 16);
    return v;
}

// ---------------------------------------------------------------------------
// S4D scan (round-3 proven version, verbatim): y = gelu(conv(u,K) + D*u),
// one (b,h) row per WAVE via LDS-staged u, 64 elems/lane.
// grid (H/4, B), block 256 = 4 independent waves.
// ---------------------------------------------------------------------------
__global__ __launch_bounds__(256) void s4_scan_kernel(
    const float* __restrict__ hT,          // (B,H,L) f32
    unsigned short* __restrict__ yT,       // (B,H,L) bf16 out
    const float* __restrict__ log_dt,
    const float* __restrict__ log_A_real,
    const float* __restrict__ A_imag,
    const float* __restrict__ C_re,
    const float* __restrict__ C_im,
    const float* __restrict__ D_skip)
{
    __shared__ float u_lds[4][64][65];
    const int tid = threadIdx.x;
    const int v = tid >> 6;
    const int t = tid & 63;
    const int h = blockIdx.x * 4 + v;
    const int b = blockIdx.y;

    const size_t rowbase = (size_t)(b * Hn + h) * Ln + (size_t)t * 64;
    const float* src = hT + rowbase;
    float* uL = &u_lds[v][t][0];

    #pragma unroll
    for (int j4 = 0; j4 < 16; ++j4) {
        float4 g = *(const float4*)(src + j4 * 4);
        uL[j4 * 4 + 0] = g.x; uL[j4 * 4 + 1] = g.y;
        uL[j4 * 4 + 2] = g.z; uL[j4 * 4 + 3] = g.w;
    }

    float dt = expf(log_dt[h]);
    float wr[N2n], wi[N2n], cr[N2n], ci[N2n];
    #pragma unroll
    for (int n = 0; n < N2n; ++n) {
        float lar = log_A_real[h * N2n + n];
        float aim = A_imag[h * N2n + n];
        float are = -expf(lar);
        float dre = are * dt, dimv = aim * dt;
        float mag = expf(dre);
        float s_, c_;
        sincosf(dimv, &s_, &c_);
        float w_re = mag * c_, w_im = mag * s_;
        wr[n] = w_re; wi[n] = w_im;
        float nre = w_re - 1.0f, nim = w_im;
        float inv = 1.0f / (are * are + aim * aim);
        float tre = (nre * are + nim * aim) * inv;
        float tim = (nim * are - nre * aim) * inv;
        float Cr = C_re[h * N2n + n], Ci = C_im[h * N2n + n];
        cr[n] = Cr * tre - Ci * tim;
        ci[n] = Cr * tim + Ci * tre;
    }
    const float Dsk = D_skip[h];

    // ---- phase 1: local scan (zero init); y_loc + D*u overwrites u in LDS ----
    float sr[N2n], si[N2n];
    #pragma unroll
    for (int n = 0; n < N2n; ++n) { sr[n] = 0.0f; si[n] = 0.0f; }
    #pragma unroll 4
    for (int j = 0; j < 64; ++j) {
        float u = uL[j];
        float acc = 0.0f;
        #pragma unroll
        for (int n = 0; n < N2n; ++n) {
            float nr = fmaf(wr[n], sr[n], fmaf(-wi[n], si[n], u));
            float ni = fmaf(wi[n], sr[n], wr[n] * si[n]);
            sr[n] = nr; si[n] = ni;
            acc = fmaf(cr[n], nr, fmaf(-ci[n], ni, acc));
        }
        uL[j] = fmaf(2.0f, acc, Dsk * u);
    }

    // ---- phase 2: inclusive wave scan of end-states, multiplier w^64 ----
    float mr[N2n], mi[N2n];
    #pragma unroll
    for (int n = 0; n < N2n; ++n) {
        float ar = wr[n], ai = wi[n];
        #pragma unroll
        for (int q = 0; q < 6; ++q) { float nr2 = ar * ar - ai * ai; ai = 2.0f * ar * ai; ar = nr2; }
        mr[n] = ar; mi[n] = ai;   // w^64
    }
    for (int dlt = 1; dlt < 64; dlt <<= 1) {
        #pragma unroll
        for (int n = 0; n < N2n; ++n) {
            float tr = __shfl_up(sr[n], (unsigned)dlt, 64);
            float ti = __shfl_up(si[n], (unsigned)dlt, 64);
            float trz = (t >= dlt) ? tr : 0.0f;
            float tiz = (t >= dlt) ? ti : 0.0f;
            sr[n] = fmaf(mr[n], trz, fmaf(-mi[n], tiz, sr[n]));
            si[n] = fmaf(mr[n], tiz, fmaf(mi[n], trz, si[n]));
        }
        #pragma unroll
        for (int n = 0; n < N2n; ++n) {
            float nr2 = mr[n] * mr[n] - mi[n] * mi[n];
            mi[n] = 2.0f * mr[n] * mi[n];
            mr[n] = nr2;
        }
    }
    float pr[N2n], pim[N2n];
    #pragma unroll
    for (int n = 0; n < N2n; ++n) {
        float er = __shfl_up(sr[n], 1u, 64);
        float ei = __shfl_up(si[n], 1u, 64);
        pr[n]  = (t >= 1) ? er : 0.0f;
        pim[n] = (t >= 1) ? ei : 0.0f;
    }

    // ---- phase 3: add correction 2*Re(Ck * w^(j+1) * p), gelu, store bf16 ----
    float dr2[N2n], di2[N2n];
    #pragma unroll
    for (int n = 0; n < N2n; ++n) { dr2[n] = cr[n]; di2[n] = ci[n]; }
    unsigned short* dst = yT + rowbase;
    for (int j8 = 0; j8 < 8; ++j8) {
        unsigned short rs[8];
        #pragma unroll
        for (int c = 0; c < 8; ++c) {
            float corr = 0.0f;
            #pragma unroll
            for (int n = 0; n < N2n; ++n) {
                float nr2 = dr2[n] * wr[n] - di2[n] * wi[n];
                float ni2 = dr2[n] * wi[n] + di2[n] * wr[n];
                dr2[n] = nr2; di2[n] = ni2;
                corr = fmaf(nr2, pr[n], fmaf(-ni2, pim[n], corr));
            }
            float yv = fmaf(2.0f, corr, uL[j8 * 8 + c]);
            rs[c] = f2bf(gelu_f(yv));
        }
        uint4 o;
        o.x = (unsigned)rs[0] | ((unsigned)rs[1] << 16);
        o.y = (unsigned)rs[2] | ((unsigned)rs[3] << 16);
        o.z = (unsigned)rs[4] | ((unsigned)rs[5] << 16);
        o.w = (unsigned)rs[6] | ((unsigned)rs[7] << 16);
        *(uint4*)(dst + j8 * 8) = o;
    }
}

// ---------------------------------------------------------------------------
// MFMA GEMM, residual-in-hT edition.
//   C_raw(M,256) = A(M,KDIM) @ W^T (+bias, GLU gate)
//   KMAJ:  A read directly from yT (B,H,L) bf16 via in-kernel LDS transpose
//          (replaces the old t16 kernel).  ACVT: A = f32 row-major (encoder).
//   LAST=0: hT[b][n][l] += C_raw  (in-place RMW, block-owned region;
//           encoder GLU=0: plain store).  No (B,L,H) h write at all.
//   LAST=1: Hout(B,L,H) = C_raw + hT  (resid read coalesced, double
//           transpose via LDS, float4 stores).
// 128x64 tile, BK=64, 4 waves (2x2), grid (256,4) -> 4 blocks/CU.
// ---------------------------------------------------------------------------
template<int KDIM, bool GLU, bool ACVT, bool KMAJ, bool LAST>
__global__ __launch_bounds__(256) void mfma_gemm(
    const unsigned short* __restrict__ Abf,   // KMAJ: yT (B,H,L)
    const float* __restrict__ Af,             // ACVT: x (M,KDIM) f32
    const float* __restrict__ W,
    const float* __restrict__ ba,
    const float* __restrict__ bg,
    float* hTbuf,                             // (B,256,L) f32 residual stream
    float* Hout)                              // LAST only: (M,256) f32
{
    constexpr int SM_MAIN = 128 * 72 * 2 + (GLU ? 2 : 1) * 64 * 72 * 2;
    constexpr int SM_TS = 64 * 132 * 4;
    constexpr int SM = SM_MAIN > SM_TS ? SM_MAIN : SM_TS;
    __shared__ __align__(16) char smem[SM];
    unsigned short* As  = (unsigned short*)smem;   // [128 rows][72] (row = m or l)
    unsigned short* Bs0 = As + 128 * 72;           // [64][72]
    unsigned short* Bs1 = Bs0 + 64 * 72;           // GLU only
    float* ts = (float*)smem;                      // [64 n][132] reused after k-loop

    const int tid = threadIdx.x;
    const int lane = tid & 63, w = tid >> 6;
    const int wm = w >> 1, wn = w & 1;
    const int lr = lane & 15, lq = lane >> 4;
    const int row0 = blockIdx.x * 128;
    const int n0 = blockIdx.y * 64;
    const int bb = row0 >> 12;
    const int l0 = row0 & (Ln - 1);

    f32x4 accA[4][2], accG[4][2];
    #pragma unroll
    for (int i = 0; i < 4; ++i)
        #pragma unroll
        for (int j = 0; j < 2; ++j) {
            accA[i][j] = (f32x4)0.0f;
            if constexpr (GLU) accG[i][j] = (f32x4)0.0f;
        }

    for (int kt = 0; kt < KDIM / 64; ++kt) {
        const int k0 = kt * 64;
        // ---- stage A ----
        if constexpr (ACVT) {
            // row-major f32 (encoder): As[m][k], pitch 72
            #pragma unroll
            for (int it = 0; it < 4; ++it) {
                int idx = it * 256 + tid; int m = idx >> 3, q = idx & 7;
                const float* s = Af + (size_t)(row0 + m) * KDIM + k0 + q * 8;
                float4 g1 = *(const float4*)s;
                float4 g2 = *(const float4*)(s + 4);
                *(uint4*)(&As[m * 72 + q * 8]) = pack8(g1, g2);
            }
        } else {
            // KMAJ: A[l][k] = yT[b][k0+p][l0+l]; read 8 l-contig bf16,
            // write transposed (8 scalar shorts down column p).
            // p = tid>>2 (64 rows, in-wave spans 16 -> LDS writes <=8-way);
            // c = (tid&3)+4*it (16 l-chunks; 4 lanes/row = 64B coalesced).
            #pragma unroll
            for (int it = 0; it < 4; ++it) {
                int p = tid >> 2;
                int c = (tid & 3) | (it << 2);
                uint4 g = *(const uint4*)(Abf + (size_t)(bb * Hn + k0 + p) * Ln + l0 + c * 8);
                unsigned short* d = &As[(c * 8) * 72 + p];
                d[0 * 72] = g.x & 0xffff; d[1 * 72] = g.x >> 16;
                d[2 * 72] = g.y & 0xffff; d[3 * 72] = g.y >> 16;
                d[4 * 72] = g.z & 0xffff; d[5 * 72] = g.z >> 16;
                d[6 * 72] = g.w & 0xffff; d[7 * 72] = g.w >> 16;
            }
        }
        // ---- stage B (64 rows x 64 k, f32 -> bf16, L2-resident weights) ----
        #pragma unroll
        for (int it = 0; it < 2; ++it) {
            int idx = it * 256 + tid; int p = idx >> 3, q = idx & 7;
            {
                const float* s = W + (size_t)(n0 + p) * KDIM + k0 + q * 8;
                float4 g1 = *(const float4*)s;
                float4 g2 = *(const float4*)(s + 4);
                *(uint4*)(&Bs0[p * 72 + q * 8]) = pack8(g1, g2);
            }
            if constexpr (GLU) {
                const float* s = W + (size_t)(256 + n0 + p) * KDIM + k0 + q * 8;
                float4 g1 = *(const float4*)s;
                float4 g2 = *(const float4*)(s + 4);
                *(uint4*)(&Bs1[p * 72 + q * 8]) = pack8(g1, g2);
            }
        }
        __syncthreads();
        // ---- MFMA: wave tile 64x32 ----
        #pragma unroll
        for (int kf = 0; kf < 2; ++kf) {
            bf16x8 av[4], bv[2], gv[2];
            #pragma unroll
            for (int mf = 0; mf < 4; ++mf)
                av[mf] = *(const bf16x8*)(&As[(wm * 64 + mf * 16 + lr) * 72 + (kf * 4 + lq) * 8]);
            #pragma unroll
            for (int nf = 0; nf < 2; ++nf) {
                bv[nf] = *(const bf16x8*)(&Bs0[(wn * 32 + nf * 16 + lr) * 72 + (kf * 4 + lq) * 8]);
                if constexpr (GLU)
                    gv[nf] = *(const bf16x8*)(&Bs1[(wn * 32 + nf * 16 + lr) * 72 + (kf * 4 + lq) * 8]);
            }
            #pragma unroll
            for (int mf = 0; mf < 4; ++mf)
                #pragma unroll
                for (int nf = 0; nf < 2; ++nf) {
                    accA[mf][nf] = __builtin_amdgcn_mfma_f32_16x16x32_bf16(av[mf], bv[nf], accA[mf][nf], 0, 0, 0);
                    if constexpr (GLU)
                        accG[mf][nf] = __builtin_amdgcn_mfma_f32_16x16x32_bf16(av[mf], gv[nf], accG[mf][nf], 0, 0, 0);
                }
        }
        __syncthreads();
    }

    // ---- epilogue pass 1: raw (bias + GLU) -> ts[n_loc][m_loc], pitch 132 ----
    float bA[2], bG[2];
    #pragma unroll
    for (int nf = 0; nf < 2; ++nf) {
        int pc = n0 + wn * 32 + nf * 16 + lr;
        bA[nf] = ba[pc];
        if constexpr (GLU) bG[nf] = bg[pc];
    }
    #pragma unroll
    for (int mf = 0; mf < 4; ++mf) {
        #pragma unroll
        for (int r = 0; r < 4; ++r) {
            int m_loc = wm * 64 + mf * 16 + lq * 4 + r;
            #pragma unroll
            for (int nf = 0; nf < 2; ++nf) {
                float val;
                if constexpr (GLU) {
                    float aval = accA[mf][nf][r] + bA[nf];
                    float gval = accG[mf][nf][r] + bG[nf];
                    val = aval * sigmoid_f(gval);
                } else {
                    val = accA[mf][nf][r] + bA[nf];
                }
                ts[(wn * 32 + nf * 16 + lr) * 132 + m_loc] = val;
            }
        }
    }
    __syncthreads();

    if constexpr (!LAST) {
        // ---- pass 2: hT[b][n0+nn][l0+m] (+)= ts  (coalesced float4 RMW) ----
        #pragma unroll
        for (int it2 = 0; it2 < 8; ++it2) {
            int idx = it2 * 256 + tid;
            int nn = idx >> 5, m4 = (idx & 31) * 4;
            float4 o = *(const float4*)(&ts[nn * 132 + m4]);
            float* gp = hTbuf + (size_t)(bb * Hn + n0 + nn) * Ln + l0 + m4;
            if constexpr (GLU) {
                float4 rr = *(const float4*)gp;
                o.x += rr.x; o.y += rr.y; o.z += rr.z; o.w += rr.w;
            }
            *(float4*)gp = o;
        }
    } else {
        // ---- pass 2: add resid (coalesced hT read), write back to ts ----
        #pragma unroll
        for (int it2 = 0; it2 < 8; ++it2) {
            int idx = it2 * 256 + tid;
            int nn = idx >> 5, m4 = (idx & 31) * 4;
            float4 o = *(const float4*)(&ts[nn * 132 + m4]);
            const float* gp = hTbuf + (size_t)(bb * Hn + n0 + nn) * Ln + l0 + m4;
            float4 rr = *(const float4*)gp;
            o.x += rr.x; o.y += rr.y; o.z += rr.z; o.w += rr.w;
            *(float4*)(&ts[nn * 132 + m4]) = o;
        }
        __syncthreads();
        // ---- pass 3: transpose out of ts, coalesced float4 Hout stores ----
        #pragma unroll
        for (int it2 = 0; it2 < 8; ++it2) {
            int idx = it2 * 256 + tid;
            int m = idx >> 4, n4 = (idx & 15) * 4;
            float4 o;
            o.x = ts[(n4 + 0) * 132 + m];
            o.y = ts[(n4 + 1) * 132 + m];
            o.z = ts[(n4 + 2) * 132 + m];
            o.w = ts[(n4 + 3) * 132 + m];
            *(float4*)(Hout + (size_t)(row0 + m) * Hn + n0 + n4) = o;
        }
    }
}

extern "C" void kernel_launch(void* const* d_in, const int* in_sizes, int n_in,
                              void* d_out, int out_size, void* d_ws, size_t ws_size,
                              hipStream_t stream) {
    (void)in_sizes; (void)n_in; (void)out_size; (void)ws_size;
    const float* x          = (const float*)d_in[0];
    const float* enc_w      = (const float*)d_in[1];
    const float* enc_b      = (const float*)d_in[2];
    const float* log_dt     = (const float*)d_in[3];
    const float* log_A_real = (const float*)d_in[4];
    const float* A_imag     = (const float*)d_in[5];
    const float* C_re       = (const float*)d_in[6];
    const float* C_im       = (const float*)d_in[7];
    const float* D_skip     = (const float*)d_in[8];
    const float* out_w      = (const float*)d_in[9];
    const float* out_b      = (const float*)d_in[10];

    const size_t NE = (size_t)Bn * Hn * Ln;
    float* h  = (float*)d_out;                        // (B,L,H) final output only
    float* hT = (float*)d_ws;                         // (B,256,L) f32 residual stream
    unsigned short* yT = (unsigned short*)(hT + NE);  // (B,H,L) bf16 scan output

    const dim3 gg(256, 4), gb(256);

    // encoder: hT = (x @ enc_w^T + enc_b)^T
    mfma_gemm<DINn, false, true, false, false><<<gg, gb, 0, stream>>>(
        nullptr, x, enc_w, enc_b, nullptr, hT, nullptr);

    for (int i = 0; i < NLn; ++i) {
        s4_scan_kernel<<<dim3(Hn / 4, Bn), gb, 0, stream>>>(
            hT, yT,
            log_dt + (size_t)i * Hn,
            log_A_real + (size_t)i * Hn * N2n,
            A_imag + (size_t)i * Hn * N2n,
            C_re + (size_t)i * Hn * N2n,
            C_im + (size_t)i * Hn * N2n,
            D_skip + (size_t)i * Hn);
        const float* wlay = out_w + (size_t)i * 2 * Hn * Hn;
        const float* bl = out_b + (size_t)i * 2 * Hn;
        if (i == NLn - 1) {
            mfma_gemm<Hn, true, false, true, true><<<gg, gb, 0, stream>>>(
                yT, nullptr, wlay, bl, bl + Hn, hT, h);
        } else {
            mfma_gemm<Hn, true, false, true, false><<<gg, gb, 0, stream>>>(
                yT, nullptr, wlay, bl, bl + Hn, hT, nullptr);
        }
    }
}